// Round 8
// baseline (822.214 us; speedup 1.0000x reference)
//
#include <hip/hip_runtime.h>

// InverseTransitionModel, B=32768, H=256, 10 GRU steps.
// v15 = v14 skeleton + async weight staging:
//   - h0/h1 single-buffered in LDS (v14's barriers already separate all
//     sweep-reads from epilogue-writes -> no stash, no new barriers). -67 KB.
//   - gates r,z of the 3 big sweeps staged through a per-wave private LDS
//     double-buffer via __builtin_amdgcn_global_load_lds width=16 (zero
//     VGPR cost for in-flight data); gate n rotates through 2 reg sets.
//   - counted s_waitcnt vmcnt(3) per kc (vmcnt(0) only at peeled last kc).
//   LDS: 33.8(h0)+33.8(h1)+1(avs)+8(bias)+64(wstage) = 140.6 KB.

#define HS 264   // LDS row stride in shorts (16B-aligned rows)

typedef __attribute__((ext_vector_type(8))) short short8;
typedef __attribute__((ext_vector_type(4))) float fvec4;

__device__ __forceinline__ float bf2f(unsigned short u) {
    union { unsigned int u; float f; } x; x.u = ((unsigned int)u) << 16; return x.f;
}
__device__ __forceinline__ unsigned short f2bf(float f) {
    union { float f; unsigned int u; } x; x.f = f;
    unsigned int r = x.u + 0x7fffu + ((x.u >> 16) & 1u);   // RNE
    return (unsigned short)(r >> 16);
}
__device__ __forceinline__ float sigm(float x)   { return __builtin_amdgcn_rcpf(1.f + __expf(-x)); }
__device__ __forceinline__ float tanh_f(float x) { return 2.f * __builtin_amdgcn_rcpf(1.f + __expf(-2.f * x)) - 1.f; }

__device__ __forceinline__ short8 ld8(const unsigned short* p) {
    return *reinterpret_cast<const short8*>(p);
}
__device__ __forceinline__ fvec4 mfma16(short8 a, short8 b, fvec4 c) {
    return __builtin_amdgcn_mfma_f32_16x16x32_bf16(a, b, c, 0, 0, 0);
}
__device__ __forceinline__ fvec4 splat4(float v) {
    fvec4 r = {v, v, v, v}; return r;
}
// async 16B/lane global->LDS: per-lane global src, wave-uniform LDS base
// (HW writes base + lane*16). size must be a literal.
__device__ __forceinline__ void gload16(const unsigned short* g, unsigned short* l) {
    __builtin_amdgcn_global_load_lds(
        (const __attribute__((address_space(1))) unsigned int*)g,
        (__attribute__((address_space(3))) unsigned int*)l, 16, 0, 0);
}

// fragment-pack offset: element (n,k) of an NxK matrix -> packed index.
// tile (n>>4, k>>5) holds 512 elems, lane-major: lane = ((k>>3)&3)*16 + (n&15),
// j = k&7. Lane l's 8 elems contiguous -> ld8 at base + lane*8 coalesces.
__device__ __forceinline__ int packoff(int e, int K) {
    const int n = e / K, k = e % K;
    return (((n >> 4) * (K >> 5) + (k >> 5)) << 9)
         + (((((k >> 3) & 3) << 4) | (n & 15)) << 3) + (k & 7);
}

// ---------------- weight cast fp32 -> bf16 + fragment packing ----------------
// ws short layout: W1[262144] W2[65536] Winit[131072] Wih0[6144 plain]
//                  Whh0[196608] Wih1[196608] Whh1[196608] Wa[2048 plain]
__global__ __launch_bounds__(256) void k_prep(
    const float* __restrict__ W1, const float* __restrict__ W2,
    const float* __restrict__ Winit, const float* __restrict__ Wih0,
    const float* __restrict__ Whh0, const float* __restrict__ Wih1,
    const float* __restrict__ Whh1, const float* __restrict__ Wa,
    unsigned short* __restrict__ wb)
{
    int i = blockIdx.x * 256 + threadIdx.x;
    if (i >= 1056768) return;
    float v; int dst;
    if (i < 262144) {
        v = W1[i];                dst = packoff(i, 1024);
    } else if (i < 327680) {
        int e = i - 262144;  v = W2[e];    dst = 262144 + packoff(e, 256);
    } else if (i < 458752) {
        int e = i - 327680;  v = Winit[e]; dst = 327680 + packoff(e, 256);
    } else if (i < 464896) {
        v = Wih0[i - 458752];     dst = i;
    } else if (i < 661504) {
        int e = i - 464896;  v = Whh0[e];  dst = 464896 + packoff(e, 256);
    } else if (i < 858112) {
        int e = i - 661504;  v = Wih1[e];  dst = 661504 + packoff(e, 256);
    } else if (i < 1054720) {
        int e = i - 858112;  v = Whh1[e];  dst = 858112 + packoff(e, 256);
    } else {
        v = Wa[i - 1054720];      dst = i;
    }
    wb[dst] = f2bf(v);
}

// ---------------- encoder: fc1 -> LN -> ReLU -> fc2 -> ReLU -> init -----------
// block = 64 rows, 8 waves; wave w -> cols [w*32, w*32+32).
// fc1 input staged via LDS (double-buffered, coalesced 16B/thread loads).
__global__ __launch_bounds__(512, 2) void k_encode(
    const float* __restrict__ ini, const float* __restrict__ fin,
    const unsigned short* __restrict__ W1b, const float* __restrict__ b1,
    const float* __restrict__ lng, const float* __restrict__ lnb,
    const unsigned short* __restrict__ W2b, const float* __restrict__ b2,
    const unsigned short* __restrict__ Winitb, const float* __restrict__ binit,
    unsigned short* __restrict__ h0g, unsigned short* __restrict__ h1g)
{
    __shared__ unsigned short hb[64 * HS];
    __shared__ unsigned short at[2][64 * 40];   // fc1 A-tiles, pad-40 stride
    __shared__ float ps[64][8][2];
    __shared__ float st[64][2];
    const int tid = threadIdx.x, lane = tid & 63, w = tid >> 6;
    const int l15 = lane & 15, q = lane >> 4;
    const int rows0 = blockIdx.x * 64;
    const int c0 = w * 32;
    const fvec4 fz = {0.f, 0.f, 0.f, 0.f};

    // stage thread-mapping for fc1 A-tiles: 64 rows x 32 k fp32 per chunk
    const int srow = tid >> 3, sseg = (tid & 7) * 4;

    // ---- fc1: [64,1024] @ W1^T (staged A) ----
    fvec4 acc[4][2];
#pragma unroll
    for (int rt = 0; rt < 4; ++rt) { acc[rt][0] = fz; acc[rt][1] = fz; }
    {
        // stage chunk 0
        const float* src0 = ini + (rows0 + srow) * 512 + sseg;
        fvec4 v = *reinterpret_cast<const fvec4*>(src0);
        union { unsigned short s[4]; unsigned long long u; } p;
        p.s[0] = f2bf(v[0]); p.s[1] = f2bf(v[1]); p.s[2] = f2bf(v[2]); p.s[3] = f2bf(v[3]);
        *reinterpret_cast<unsigned long long*>(&at[0][srow * 40 + sseg]) = p.u;
    }
    __syncthreads();
#pragma unroll 1
    for (int kc = 0; kc < 32; ++kc) {
        const int buf = kc & 1;
        if (kc < 31) {   // stage chunk kc+1 into other buffer
            const int k0 = (kc + 1) * 32 + sseg;
            const float* src = (k0 < 512) ? (ini + (rows0 + srow) * 512 + k0)
                                          : (fin + (rows0 + srow) * 512 + (k0 - 512));
            fvec4 v = *reinterpret_cast<const fvec4*>(src);
            union { unsigned short s[4]; unsigned long long u; } p;
            p.s[0] = f2bf(v[0]); p.s[1] = f2bf(v[1]); p.s[2] = f2bf(v[2]); p.s[3] = f2bf(v[3]);
            *reinterpret_cast<unsigned long long*>(&at[buf ^ 1][srow * 40 + sseg]) = p.u;
        }
        short8 b8a = ld8(W1b + (((w * 2 + 0) * 32 + kc) * 64 + lane) * 8);
        short8 b8b = ld8(W1b + (((w * 2 + 1) * 32 + kc) * 64 + lane) * 8);
        short8 a8[4];
#pragma unroll
        for (int rt = 0; rt < 4; ++rt)
            a8[rt] = ld8(&at[buf][(rt * 16 + l15) * 40 + q * 8]);
#pragma unroll
        for (int rt = 0; rt < 4; ++rt) {
            acc[rt][0] = mfma16(a8[rt], b8a, acc[rt][0]);
            acc[rt][1] = mfma16(a8[rt], b8b, acc[rt][1]);
        }
        __syncthreads();
    }
    // ---- bias + LN stats ----
    float bv[2] = { b1[c0 + l15], b1[c0 + 16 + l15] };
#pragma unroll
    for (int rt = 0; rt < 4; ++rt)
#pragma unroll
        for (int r = 0; r < 4; ++r) {
            float s = 0.f, s2 = 0.f;
#pragma unroll
            for (int ct = 0; ct < 2; ++ct) {
                float v = acc[rt][ct][r] + bv[ct];
                acc[rt][ct][r] = v;
                s += v; s2 += v * v;
            }
#pragma unroll
            for (int off = 1; off < 16; off <<= 1) {
                s  += __shfl_xor(s,  off, 64);
                s2 += __shfl_xor(s2, off, 64);
            }
            if (l15 == 0) {
                int row = rt * 16 + q * 4 + r;
                ps[row][w][0] = s; ps[row][w][1] = s2;
            }
        }
    __syncthreads();
    if (tid < 64) {
        float s = 0.f, s2 = 0.f;
#pragma unroll
        for (int j = 0; j < 8; ++j) { s += ps[tid][j][0]; s2 += ps[tid][j][1]; }
        float mu = s * (1.f / 256.f);
        float var = s2 * (1.f / 256.f) - mu * mu;
        st[tid][0] = mu; st[tid][1] = rsqrtf(var + 1e-5f);
    }
    __syncthreads();
    {
        float gv[2]  = { lng[c0 + l15], lng[c0 + 16 + l15] };
        float bbv[2] = { lnb[c0 + l15], lnb[c0 + 16 + l15] };
#pragma unroll
        for (int rt = 0; rt < 4; ++rt)
#pragma unroll
            for (int ct = 0; ct < 2; ++ct)
#pragma unroll
                for (int r = 0; r < 4; ++r) {
                    int row = rt * 16 + q * 4 + r;
                    float v = (acc[rt][ct][r] - st[row][0]) * st[row][1] * gv[ct] + bbv[ct];
                    v = fmaxf(v, 0.f);
                    hb[row * HS + c0 + ct * 16 + l15] = f2bf(v);
                }
    }
    __syncthreads();
    // ---- fc2: relu(hb @ W2^T + b2), in-place on hb ----
    fvec4 acc2[4][2];
#pragma unroll
    for (int rt = 0; rt < 4; ++rt) { acc2[rt][0] = fz; acc2[rt][1] = fz; }
#pragma unroll 2
    for (int kc = 0; kc < 8; ++kc) {
        const int k0 = kc * 32 + q * 8;
        short8 a8[4];
#pragma unroll
        for (int rt = 0; rt < 4; ++rt) a8[rt] = ld8(hb + (rt * 16 + l15) * HS + k0);
#pragma unroll
        for (int ct = 0; ct < 2; ++ct) {
            short8 b8 = ld8(W2b + (((w * 2 + ct) * 8 + kc) * 64 + lane) * 8);
#pragma unroll
            for (int rt = 0; rt < 4; ++rt) acc2[rt][ct] = mfma16(a8[rt], b8, acc2[rt][ct]);
        }
    }
    {
        float b2v[2] = { b2[c0 + l15], b2[c0 + 16 + l15] };
        unsigned short stg[4][2][4];
#pragma unroll
        for (int rt = 0; rt < 4; ++rt)
#pragma unroll
            for (int ct = 0; ct < 2; ++ct)
#pragma unroll
                for (int r = 0; r < 4; ++r)
                    stg[rt][ct][r] = f2bf(fmaxf(acc2[rt][ct][r] + b2v[ct], 0.f));
        __syncthreads();
#pragma unroll
        for (int rt = 0; rt < 4; ++rt)
#pragma unroll
            for (int ct = 0; ct < 2; ++ct)
#pragma unroll
                for (int r = 0; r < 4; ++r)
                    hb[(rt * 16 + q * 4 + r) * HS + c0 + ct * 16 + l15] = stg[rt][ct][r];
    }
    __syncthreads();
    // ---- init: hb @ Winit^T + binit -> h0g/h1g (torch view interleave) ----
    fvec4 a3[4][4];
#pragma unroll
    for (int rt = 0; rt < 4; ++rt)
#pragma unroll
        for (int ct = 0; ct < 4; ++ct) a3[rt][ct] = fz;
#pragma unroll 1
    for (int kc = 0; kc < 8; ++kc) {
        const int k0 = kc * 32 + q * 8;
        short8 a8[4];
#pragma unroll
        for (int rt = 0; rt < 4; ++rt) a8[rt] = ld8(hb + (rt * 16 + l15) * HS + k0);
#pragma unroll
        for (int ct = 0; ct < 4; ++ct) {
            short8 b8 = ld8(Winitb + (((w * 4 + ct) * 8 + kc) * 64 + lane) * 8);
#pragma unroll
            for (int rt = 0; rt < 4; ++rt) a3[rt][ct] = mfma16(a8[rt], b8, a3[rt][ct]);
        }
    }
    const int c0i = w * 64;
#pragma unroll
    for (int ct = 0; ct < 4; ++ct) {
        const int j = c0i + ct * 16 + l15;
        const float bz = binit[j];
        const int half = j >> 8, cc = j & 255;
#pragma unroll
        for (int rt = 0; rt < 4; ++rt)
#pragma unroll
            for (int r = 0; r < 4; ++r) {
                const int i = rows0 + rt * 16 + q * 4 + r;
                const unsigned short v = f2bf(a3[rt][ct][r] + bz);
                if (i < 16384) h0g[(2 * i + half) * 256 + cc] = v;
                else           h1g[(2 * (i - 16384) + half) * 256 + cc] = v;
            }
    }
}

// ---------------- fused 10-step rollout (v15) -------------------------------
// 512 blocks x 1024 threads (16 waves, 4 waves/SIMD); wave = 64 rows x 16
// cols; 64 AGPR acc; single-buffered h0/h1 (safe under v14's barriers);
// r,z weights of each big sweep async-staged via global_load_lds into a
// per-wave private LDS dbuf; n-gate rotates through 2 reg sets.
__global__ __launch_bounds__(1024, 4) void k_roll(
    const unsigned short* __restrict__ h0g, const unsigned short* __restrict__ h1g,
    const unsigned short* __restrict__ Wih0b, const unsigned short* __restrict__ Whh0b,
    const unsigned short* __restrict__ Wih1b, const unsigned short* __restrict__ Whh1b,
    const unsigned short* __restrict__ Wab,
    const float* __restrict__ bih0, const float* __restrict__ bhh0,
    const float* __restrict__ bih1, const float* __restrict__ bhh1,
    const float* __restrict__ ba, float* __restrict__ out)
{
    __shared__ unsigned short h0s[64 * HS];
    __shared__ unsigned short h1s[64 * HS];
    __shared__ unsigned short avs[64 * 8];
    __shared__ float ldsb[2048];          // [cell0: br,bz,bi,bh][cell1: same] x 256
    __shared__ unsigned short wst[32768]; // [2 buf][16 wave][2 gate][512]
    const int tid = threadIdx.x, lane = tid & 63, w = tid >> 6;   // w: 0..15
    const int l15 = lane & 15, q = lane >> 4;
    const int rows0 = blockIdx.x * 64;
    const int c = w * 16 + l15;          // this wave's column for epilogues
    const fvec4 fz = {0.f, 0.f, 0.f, 0.f};
    const short8 z8 = {0,0,0,0,0,0,0,0};

#define WSLOT(b, g) (wst + (((b) * 16 + w) * 2 + (g)) * 512)

    // ---- h state global -> LDS; biases -> LDS ----
    for (int it = tid; it < 64 * 32; it += 1024) {
        const int row = it >> 5, g = (it & 31) * 8;
        *reinterpret_cast<short8*>(&h0s[row * HS + g]) = ld8(h0g + (rows0 + row) * 256 + g);
        *reinterpret_cast<short8*>(&h1s[row * HS + g]) = ld8(h1g + (rows0 + row) * 256 + g);
    }
    if (tid < 256) {
        const int j = tid;
        ldsb[j]       = bih0[j] + bhh0[j];
        ldsb[256 + j] = bih0[256 + j] + bhh0[256 + j];
        ldsb[512 + j] = bih0[512 + j];
        ldsb[768 + j] = bhh0[512 + j];
    } else if (tid < 512) {
        const int j = tid - 256;
        ldsb[1024 + j] = bih1[j] + bhh1[j];
        ldsb[1280 + j] = bih1[256 + j] + bhh1[256 + j];
        ldsb[1536 + j] = bih1[512 + j];
        ldsb[1792 + j] = bhh1[512 + j];
    }
    const float bav = ba[l15 & 7];
    __syncthreads();

    // prime hh0 stage for t=0
    {
        const unsigned short* g0 = Whh0b + ((w * 8 + 0) * 64 + lane) * 8;
        gload16(g0,         WSLOT(0, 0));
        gload16(g0 + 65536, WSLOT(0, 1));
    }

    for (int t = 0; t < 10; ++t) {
        // ===== phase A: w<4 logits(t-1)+softmax->avs from h1s ===============
        if (t > 0 && w < 4) {
            fvec4 f = fz;
#pragma unroll 1
            for (int kc = 0; kc < 8; ++kc) {
                const int k0 = kc * 32 + q * 8;
                short8 a8 = ld8(h1s + (w * 16 + l15) * HS + k0);
                short8 b8 = ld8(Wab + (l15 & 7) * 256 + k0);   // cols 8-15 dup, ignored
                f = mfma16(a8, b8, f);
            }
#pragma unroll
            for (int r = 0; r < 4; ++r) {
                float s = f[r] + bav;
                float m = s;
                m = fmaxf(m, __shfl_xor(m, 1, 64));
                m = fmaxf(m, __shfl_xor(m, 2, 64));
                m = fmaxf(m, __shfl_xor(m, 4, 64));
                float e = __expf(s - m);
                float se = e;
                se += __shfl_xor(se, 1, 64);
                se += __shfl_xor(se, 2, 64);
                se += __shfl_xor(se, 4, 64);
                if (l15 < 8) {
                    const int lrow = w * 16 + q * 4 + r;
                    out[(rows0 + lrow) * 80 + (t - 1) * 8 + l15] = s;
                    avs[lrow * 8 + l15] = f2bf(e * __builtin_amdgcn_rcpf(se));
                }
            }
        }
        // ===== phase B: cell0 acc init + staged hh0 sweep (reads h0s) =======
        fvec4 aR[4], aZ[4], aNi[4], aNh[4];
        {
            const float vr = ldsb[c],       vz = ldsb[256 + c];
            const float vi = ldsb[512 + c], vh = ldsb[768 + c];
#pragma unroll
            for (int rt = 0; rt < 4; ++rt) {
                aR[rt]  = splat4(vr);
                aZ[rt]  = splat4(vz);
                aNi[rt] = splat4(vi);
                aNh[rt] = splat4(vh);
            }
        }
        {
            short8 wn_nx = ld8(Whh0b + ((w * 8 + 0) * 64 + lane) * 8 + 131072);
#pragma unroll 1
            for (int kc = 0; kc < 7; ++kc) {
                const short8 wn = wn_nx;
                const unsigned short* g1 = Whh0b + ((w * 8 + kc + 1) * 64 + lane) * 8;
                gload16(g1,         WSLOT((kc + 1) & 1, 0));
                gload16(g1 + 65536, WSLOT((kc + 1) & 1, 1));
                wn_nx = ld8(g1 + 131072);
                asm volatile("s_waitcnt vmcnt(3)" ::: "memory");
                const short8 wr = ld8(WSLOT(kc & 1, 0) + lane * 8);
                const short8 wz = ld8(WSLOT(kc & 1, 1) + lane * 8);
                const int k0 = kc * 32 + q * 8;
#pragma unroll
                for (int rt = 0; rt < 4; ++rt) {
                    const short8 ah = ld8(h0s + (rt * 16 + l15) * HS + k0);
                    aR[rt]  = mfma16(ah, wr, aR[rt]);
                    aZ[rt]  = mfma16(ah, wz, aZ[rt]);
                    aNh[rt] = mfma16(ah, wn, aNh[rt]);
                }
            }
            {   // kc = 7 (peeled)
                const short8 wn = wn_nx;
                asm volatile("s_waitcnt vmcnt(0)" ::: "memory");
                const short8 wr = ld8(WSLOT(1, 0) + lane * 8);
                const short8 wz = ld8(WSLOT(1, 1) + lane * 8);
                const int k0 = 7 * 32 + q * 8;
#pragma unroll
                for (int rt = 0; rt < 4; ++rt) {
                    const short8 ah = ld8(h0s + (rt * 16 + l15) * HS + k0);
                    aR[rt]  = mfma16(ah, wr, aR[rt]);
                    aZ[rt]  = mfma16(ah, wz, aZ[rt]);
                    aNh[rt] = mfma16(ah, wn, aNh[rt]);
                }
            }
        }
        __syncthreads();   // avs visible; all phase-B h0s reads complete
        // ===== phase C: prime hh1 stage; action GEMM; epi0 -> h0s in place ==
        {
            const unsigned short* g0 = Whh1b + ((w * 8 + 0) * 64 + lane) * 8;
            gload16(g0,         WSLOT(0, 0));
            gload16(g0 + 65536, WSLOT(0, 1));
        }
        if (t > 0) {
            const unsigned short* wp = Wih0b + c * 8;
            const short8 wr = ld8(wp);
            const short8 wz = ld8(wp + 2048);
            const short8 wn = ld8(wp + 4096);
#pragma unroll
            for (int rt = 0; rt < 4; ++rt) {
                short8 v = ld8(avs + (rt * 16 + l15) * 8);
                const short8 av = (q == 0) ? v : z8;
                aR[rt]  = mfma16(av, wr, aR[rt]);
                aZ[rt]  = mfma16(av, wz, aZ[rt]);
                aNi[rt] = mfma16(av, wn, aNi[rt]);
            }
        }
#pragma unroll
        for (int rt = 0; rt < 4; ++rt)
#pragma unroll
            for (int r = 0; r < 4; ++r) {
                const int row = rt * 16 + q * 4 + r;
                const float hold = bf2f(h0s[row * HS + c]);
                const float rr = sigm(aR[rt][r]);
                const float zz = sigm(aZ[rt][r]);
                const float nn = tanh_f(aNi[rt][r] + rr * aNh[rt][r]);
                h0s[row * HS + c] = f2bf((1.f - zz) * nn + zz * hold);
            }
        // ===== phase D: cell1 acc init + staged hh1 sweep (reads h1s) =======
        fvec4 bR[4], bZ[4], bNi[4], bNh[4];
        {
            const float vr = ldsb[1024 + c], vz = ldsb[1280 + c];
            const float vi = ldsb[1536 + c], vh = ldsb[1792 + c];
#pragma unroll
            for (int rt = 0; rt < 4; ++rt) {
                bR[rt]  = splat4(vr);
                bZ[rt]  = splat4(vz);
                bNi[rt] = splat4(vi);
                bNh[rt] = splat4(vh);
            }
        }
        {
            short8 wn_nx = ld8(Whh1b + ((w * 8 + 0) * 64 + lane) * 8 + 131072);
#pragma unroll 1
            for (int kc = 0; kc < 7; ++kc) {
                const short8 wn = wn_nx;
                const unsigned short* g1 = Whh1b + ((w * 8 + kc + 1) * 64 + lane) * 8;
                gload16(g1,         WSLOT((kc + 1) & 1, 0));
                gload16(g1 + 65536, WSLOT((kc + 1) & 1, 1));
                wn_nx = ld8(g1 + 131072);
                asm volatile("s_waitcnt vmcnt(3)" ::: "memory");
                const short8 wr = ld8(WSLOT(kc & 1, 0) + lane * 8);
                const short8 wz = ld8(WSLOT(kc & 1, 1) + lane * 8);
                const int k0 = kc * 32 + q * 8;
#pragma unroll
                for (int rt = 0; rt < 4; ++rt) {
                    const short8 ah = ld8(h1s + (rt * 16 + l15) * HS + k0);
                    bR[rt]  = mfma16(ah, wr, bR[rt]);
                    bZ[rt]  = mfma16(ah, wz, bZ[rt]);
                    bNh[rt] = mfma16(ah, wn, bNh[rt]);
                }
            }
            {   // kc = 7 (peeled)
                const short8 wn = wn_nx;
                asm volatile("s_waitcnt vmcnt(0)" ::: "memory");
                const short8 wr = ld8(WSLOT(1, 0) + lane * 8);
                const short8 wz = ld8(WSLOT(1, 1) + lane * 8);
                const int k0 = 7 * 32 + q * 8;
#pragma unroll
                for (int rt = 0; rt < 4; ++rt) {
                    const short8 ah = ld8(h1s + (rt * 16 + l15) * HS + k0);
                    bR[rt]  = mfma16(ah, wr, bR[rt]);
                    bZ[rt]  = mfma16(ah, wz, bZ[rt]);
                    bNh[rt] = mfma16(ah, wn, bNh[rt]);
                }
            }
        }
        __syncthreads();   // h0s new values visible; phase-D h1s reads done
        // ===== phase E: staged ih1 sweep (reads new h0s) ====================
        {
            const unsigned short* g0 = Wih1b + ((w * 8 + 0) * 64 + lane) * 8;
            gload16(g0,         WSLOT(0, 0));
            gload16(g0 + 65536, WSLOT(0, 1));
        }
        {
            short8 wn_nx = ld8(Wih1b + ((w * 8 + 0) * 64 + lane) * 8 + 131072);
#pragma unroll 1
            for (int kc = 0; kc < 7; ++kc) {
                const short8 wn = wn_nx;
                const unsigned short* g1 = Wih1b + ((w * 8 + kc + 1) * 64 + lane) * 8;
                gload16(g1,         WSLOT((kc + 1) & 1, 0));
                gload16(g1 + 65536, WSLOT((kc + 1) & 1, 1));
                wn_nx = ld8(g1 + 131072);
                asm volatile("s_waitcnt vmcnt(3)" ::: "memory");
                const short8 wr = ld8(WSLOT(kc & 1, 0) + lane * 8);
                const short8 wz = ld8(WSLOT(kc & 1, 1) + lane * 8);
                const int k0 = kc * 32 + q * 8;
#pragma unroll
                for (int rt = 0; rt < 4; ++rt) {
                    const short8 ai = ld8(h0s + (rt * 16 + l15) * HS + k0);
                    bR[rt]  = mfma16(ai, wr, bR[rt]);
                    bZ[rt]  = mfma16(ai, wz, bZ[rt]);
                    bNi[rt] = mfma16(ai, wn, bNi[rt]);
                }
            }
            {   // kc = 7 (peeled)
                const short8 wn = wn_nx;
                asm volatile("s_waitcnt vmcnt(0)" ::: "memory");
                const short8 wr = ld8(WSLOT(1, 0) + lane * 8);
                const short8 wz = ld8(WSLOT(1, 1) + lane * 8);
                const int k0 = 7 * 32 + q * 8;
#pragma unroll
                for (int rt = 0; rt < 4; ++rt) {
                    const short8 ai = ld8(h0s + (rt * 16 + l15) * HS + k0);
                    bR[rt]  = mfma16(ai, wr, bR[rt]);
                    bZ[rt]  = mfma16(ai, wz, bZ[rt]);
                    bNi[rt] = mfma16(ai, wn, bNi[rt]);
                }
            }
        }
        // prime next step's hh0 stage (buf0 free: last read at kc=6 above)
        {
            const unsigned short* g0 = Whh0b + ((w * 8 + 0) * 64 + lane) * 8;
            gload16(g0,         WSLOT(0, 0));
            gload16(g0 + 65536, WSLOT(0, 1));
        }
        // epi1 -> h1s in place (own cols)
#pragma unroll
        for (int rt = 0; rt < 4; ++rt)
#pragma unroll
            for (int r = 0; r < 4; ++r) {
                const int row = rt * 16 + q * 4 + r;
                const float hold = bf2f(h1s[row * HS + c]);
                const float rr = sigm(bR[rt][r]);
                const float zz = sigm(bZ[rt][r]);
                const float nn = tanh_f(bNi[rt][r] + rr * bNh[rt][r]);
                h1s[row * HS + c] = f2bf((1.f - zz) * nn + zz * hold);
            }
        __syncthreads();   // h1s new values visible (next phase A reads them)
    }
    // ===== final logits (t=9) from h1s ======================================
    if (w < 4) {
        fvec4 f = fz;
#pragma unroll 1
        for (int kc = 0; kc < 8; ++kc) {
            const int k0 = kc * 32 + q * 8;
            short8 a8 = ld8(h1s + (w * 16 + l15) * HS + k0);
            short8 b8 = ld8(Wab + (l15 & 7) * 256 + k0);
            f = mfma16(a8, b8, f);
        }
#pragma unroll
        for (int r = 0; r < 4; ++r) {
            if (l15 < 8) {
                const int lrow = w * 16 + q * 4 + r;
                out[(rows0 + lrow) * 80 + 72 + l15] = f[r] + bav;
            }
        }
    }
#undef WSLOT
}

// ---------------- host side -----------------------------------------------
extern "C" void kernel_launch(void* const* d_in, const int* in_sizes, int n_in,
                              void* d_out, int out_size, void* d_ws, size_t ws_size,
                              hipStream_t stream)
{
    const float* ini   = (const float*)d_in[0];
    const float* fin   = (const float*)d_in[1];
    /* d_in[2] = horizon (always 10) */
    const float* W1    = (const float*)d_in[3];
    const float* b1    = (const float*)d_in[4];
    const float* lng   = (const float*)d_in[5];
    const float* lnb   = (const float*)d_in[6];
    const float* W2    = (const float*)d_in[7];
    const float* b2    = (const float*)d_in[8];
    const float* Wih0  = (const float*)d_in[9];
    const float* Whh0  = (const float*)d_in[10];
    const float* bih0  = (const float*)d_in[11];
    const float* bhh0  = (const float*)d_in[12];
    const float* Wih1  = (const float*)d_in[13];
    const float* Whh1  = (const float*)d_in[14];
    const float* bih1  = (const float*)d_in[15];
    const float* bhh1  = (const float*)d_in[16];
    const float* Wa    = (const float*)d_in[17];
    const float* ba    = (const float*)d_in[18];
    const float* Winit = (const float*)d_in[19];
    const float* binit = (const float*)d_in[20];
    float* out = (float*)d_out;

    char* ws = (char*)d_ws;
    unsigned short* wb     = (unsigned short*)ws;
    unsigned short* W1b    = wb;
    unsigned short* W2b    = wb + 262144;
    unsigned short* Winitb = wb + 327680;
    unsigned short* Wih0b  = wb + 458752;
    unsigned short* Whh0b  = wb + 464896;
    unsigned short* Wih1b  = wb + 661504;
    unsigned short* Whh1b  = wb + 858112;
    unsigned short* Wab    = wb + 1054720;
    unsigned short* h0g = (unsigned short*)(ws + 2113536);
    unsigned short* h1g = (unsigned short*)(ws + 18890752);

    k_prep<<<dim3(4128), dim3(256), 0, stream>>>(W1, W2, Winit, Wih0, Whh0, Wih1, Whh1, Wa, wb);
    k_encode<<<dim3(512), dim3(512), 0, stream>>>(ini, fin, W1b, b1, lng, lnb, W2b, b2,
                                                  Winitb, binit, h0g, h1g);
    k_roll<<<dim3(512), dim3(1024), 0, stream>>>(h0g, h1g, Wih0b, Whh0b, Wih1b, Whh1b, Wab,
                                                 bih0, bhh0, bih1, bhh1, ba, out);
}

// Round 10
// 665.334 us; speedup vs baseline: 1.2358x; 1.2358x over previous
//
#include <hip/hip_runtime.h>

// InverseTransitionModel, B=32768, H=256, 10 GRU steps.
// v16 (resubmit — prior round failed on infra, container error, no measurement)
// = k_roll reverted to v13 (best measured: 452us, clean counters; v15's
// async staging spilled — 62 MB scratch writes — and defeated compiler
// scheduling) + k_encode fc1 re-tiled: 64-K staged chunks (2 MFMA sub-steps
// per stage) halve the barrier count 32 -> 16.

#define HS 264   // LDS row stride in shorts (16B-aligned rows)

typedef __attribute__((ext_vector_type(8))) short short8;
typedef __attribute__((ext_vector_type(4))) float fvec4;

__device__ __forceinline__ float bf2f(unsigned short u) {
    union { unsigned int u; float f; } x; x.u = ((unsigned int)u) << 16; return x.f;
}
__device__ __forceinline__ unsigned short f2bf(float f) {
    union { float f; unsigned int u; } x; x.f = f;
    unsigned int r = x.u + 0x7fffu + ((x.u >> 16) & 1u);   // RNE
    return (unsigned short)(r >> 16);
}
__device__ __forceinline__ float sigm(float x)   { return __builtin_amdgcn_rcpf(1.f + __expf(-x)); }
__device__ __forceinline__ float tanh_f(float x) { return 2.f * __builtin_amdgcn_rcpf(1.f + __expf(-2.f * x)) - 1.f; }

__device__ __forceinline__ short8 ld8(const unsigned short* p) {
    return *reinterpret_cast<const short8*>(p);
}
__device__ __forceinline__ fvec4 mfma16(short8 a, short8 b, fvec4 c) {
    return __builtin_amdgcn_mfma_f32_16x16x32_bf16(a, b, c, 0, 0, 0);
}
__device__ __forceinline__ fvec4 splat4(float v) {
    fvec4 r = {v, v, v, v}; return r;
}

// fragment-pack offset: element (n,k) of an NxK matrix -> packed index.
// tile (n>>4, k>>5) holds 512 elems, lane-major: lane = ((k>>3)&3)*16 + (n&15),
// j = k&7. Lane l's 8 elems contiguous -> ld8 at base + lane*8 coalesces.
__device__ __forceinline__ int packoff(int e, int K) {
    const int n = e / K, k = e % K;
    return (((n >> 4) * (K >> 5) + (k >> 5)) << 9)
         + (((((k >> 3) & 3) << 4) | (n & 15)) << 3) + (k & 7);
}

// ---------------- weight cast fp32 -> bf16 + fragment packing ----------------
// ws short layout: W1[262144] W2[65536] Winit[131072] Wih0[6144 plain]
//                  Whh0[196608] Wih1[196608] Whh1[196608] Wa[2048 plain]
__global__ __launch_bounds__(256) void k_prep(
    const float* __restrict__ W1, const float* __restrict__ W2,
    const float* __restrict__ Winit, const float* __restrict__ Wih0,
    const float* __restrict__ Whh0, const float* __restrict__ Wih1,
    const float* __restrict__ Whh1, const float* __restrict__ Wa,
    unsigned short* __restrict__ wb)
{
    int i = blockIdx.x * 256 + threadIdx.x;
    if (i >= 1056768) return;
    float v; int dst;
    if (i < 262144) {
        v = W1[i];                dst = packoff(i, 1024);
    } else if (i < 327680) {
        int e = i - 262144;  v = W2[e];    dst = 262144 + packoff(e, 256);
    } else if (i < 458752) {
        int e = i - 327680;  v = Winit[e]; dst = 327680 + packoff(e, 256);
    } else if (i < 464896) {
        v = Wih0[i - 458752];     dst = i;
    } else if (i < 661504) {
        int e = i - 464896;  v = Whh0[e];  dst = 464896 + packoff(e, 256);
    } else if (i < 858112) {
        int e = i - 661504;  v = Wih1[e];  dst = 661504 + packoff(e, 256);
    } else if (i < 1054720) {
        int e = i - 858112;  v = Whh1[e];  dst = 858112 + packoff(e, 256);
    } else {
        v = Wa[i - 1054720];      dst = i;
    }
    wb[dst] = f2bf(v);
}

// ---------------- encoder: fc1 -> LN -> ReLU -> fc2 -> ReLU -> init -----------
// block = 64 rows, 8 waves; wave w -> cols [w*32, w*32+32).
// fc1 input staged via LDS in 64-K chunks (double-buffered, 16 barriers).
__global__ __launch_bounds__(512, 2) void k_encode(
    const float* __restrict__ ini, const float* __restrict__ fin,
    const unsigned short* __restrict__ W1b, const float* __restrict__ b1,
    const float* __restrict__ lng, const float* __restrict__ lnb,
    const unsigned short* __restrict__ W2b, const float* __restrict__ b2,
    const unsigned short* __restrict__ Winitb, const float* __restrict__ binit,
    unsigned short* __restrict__ h0g, unsigned short* __restrict__ h1g)
{
    __shared__ unsigned short hb[64 * HS];
    __shared__ unsigned short at[2][64 * 72];   // fc1 A-tiles: 64 rows x 64 k, pad-72
    __shared__ float ps[64][8][2];
    __shared__ float st[64][2];
    const int tid = threadIdx.x, lane = tid & 63, w = tid >> 6;
    const int l15 = lane & 15, q = lane >> 4;
    const int rows0 = blockIdx.x * 64;
    const int c0 = w * 32;
    const fvec4 fz = {0.f, 0.f, 0.f, 0.f};

    // stage mapping: 64 rows x 64 k fp32 per chunk; 8 thr/row x 8 fp32/thr
    const int srow = tid >> 3, sseg = (tid & 7) * 8;

    // ---- fc1: [64,1024] @ W1^T (staged A, 64-K chunks) ----
    fvec4 acc[4][2];
#pragma unroll
    for (int rt = 0; rt < 4; ++rt) { acc[rt][0] = fz; acc[rt][1] = fz; }
    {
        // stage chunk 0 (k0 range [sseg, sseg+8) within chunk, never straddles 512)
        const int k0 = sseg;
        const float* src = ini + (rows0 + srow) * 512 + k0;
        fvec4 v0 = *reinterpret_cast<const fvec4*>(src);
        fvec4 v1 = *reinterpret_cast<const fvec4*>(src + 4);
        union { unsigned short s[8]; short8 v; } p;
        p.s[0] = f2bf(v0[0]); p.s[1] = f2bf(v0[1]); p.s[2] = f2bf(v0[2]); p.s[3] = f2bf(v0[3]);
        p.s[4] = f2bf(v1[0]); p.s[5] = f2bf(v1[1]); p.s[6] = f2bf(v1[2]); p.s[7] = f2bf(v1[3]);
        *reinterpret_cast<short8*>(&at[0][srow * 72 + sseg]) = p.v;
    }
    __syncthreads();
#pragma unroll 1
    for (int ch = 0; ch < 16; ++ch) {
        const int buf = ch & 1;
        if (ch < 15) {   // stage chunk ch+1 into other buffer
            const int k0 = (ch + 1) * 64 + sseg;
            const float* src = (k0 < 512) ? (ini + (rows0 + srow) * 512 + k0)
                                          : (fin + (rows0 + srow) * 512 + (k0 - 512));
            fvec4 v0 = *reinterpret_cast<const fvec4*>(src);
            fvec4 v1 = *reinterpret_cast<const fvec4*>(src + 4);
            union { unsigned short s[8]; short8 v; } p;
            p.s[0] = f2bf(v0[0]); p.s[1] = f2bf(v0[1]); p.s[2] = f2bf(v0[2]); p.s[3] = f2bf(v0[3]);
            p.s[4] = f2bf(v1[0]); p.s[5] = f2bf(v1[1]); p.s[6] = f2bf(v1[2]); p.s[7] = f2bf(v1[3]);
            *reinterpret_cast<short8*>(&at[buf ^ 1][srow * 72 + sseg]) = p.v;
        }
#pragma unroll
        for (int s = 0; s < 2; ++s) {
            const int kc = ch * 2 + s;
            short8 b8a = ld8(W1b + (((w * 2 + 0) * 32 + kc) * 64 + lane) * 8);
            short8 b8b = ld8(W1b + (((w * 2 + 1) * 32 + kc) * 64 + lane) * 8);
            short8 a8[4];
#pragma unroll
            for (int rt = 0; rt < 4; ++rt)
                a8[rt] = ld8(&at[buf][(rt * 16 + l15) * 72 + s * 32 + q * 8]);
#pragma unroll
            for (int rt = 0; rt < 4; ++rt) {
                acc[rt][0] = mfma16(a8[rt], b8a, acc[rt][0]);
                acc[rt][1] = mfma16(a8[rt], b8b, acc[rt][1]);
            }
        }
        __syncthreads();
    }
    // ---- bias + LN stats ----
    float bv[2] = { b1[c0 + l15], b1[c0 + 16 + l15] };
#pragma unroll
    for (int rt = 0; rt < 4; ++rt)
#pragma unroll
        for (int r = 0; r < 4; ++r) {
            float s = 0.f, s2 = 0.f;
#pragma unroll
            for (int ct = 0; ct < 2; ++ct) {
                float v = acc[rt][ct][r] + bv[ct];
                acc[rt][ct][r] = v;
                s += v; s2 += v * v;
            }
#pragma unroll
            for (int off = 1; off < 16; off <<= 1) {
                s  += __shfl_xor(s,  off, 64);
                s2 += __shfl_xor(s2, off, 64);
            }
            if (l15 == 0) {
                int row = rt * 16 + q * 4 + r;
                ps[row][w][0] = s; ps[row][w][1] = s2;
            }
        }
    __syncthreads();
    if (tid < 64) {
        float s = 0.f, s2 = 0.f;
#pragma unroll
        for (int j = 0; j < 8; ++j) { s += ps[tid][j][0]; s2 += ps[tid][j][1]; }
        float mu = s * (1.f / 256.f);
        float var = s2 * (1.f / 256.f) - mu * mu;
        st[tid][0] = mu; st[tid][1] = rsqrtf(var + 1e-5f);
    }
    __syncthreads();
    {
        float gv[2]  = { lng[c0 + l15], lng[c0 + 16 + l15] };
        float bbv[2] = { lnb[c0 + l15], lnb[c0 + 16 + l15] };
#pragma unroll
        for (int rt = 0; rt < 4; ++rt)
#pragma unroll
            for (int ct = 0; ct < 2; ++ct)
#pragma unroll
                for (int r = 0; r < 4; ++r) {
                    int row = rt * 16 + q * 4 + r;
                    float v = (acc[rt][ct][r] - st[row][0]) * st[row][1] * gv[ct] + bbv[ct];
                    v = fmaxf(v, 0.f);
                    hb[row * HS + c0 + ct * 16 + l15] = f2bf(v);
                }
    }
    __syncthreads();
    // ---- fc2: relu(hb @ W2^T + b2), in-place on hb ----
    fvec4 acc2[4][2];
#pragma unroll
    for (int rt = 0; rt < 4; ++rt) { acc2[rt][0] = fz; acc2[rt][1] = fz; }
#pragma unroll 2
    for (int kc = 0; kc < 8; ++kc) {
        const int k0 = kc * 32 + q * 8;
        short8 a8[4];
#pragma unroll
        for (int rt = 0; rt < 4; ++rt) a8[rt] = ld8(hb + (rt * 16 + l15) * HS + k0);
#pragma unroll
        for (int ct = 0; ct < 2; ++ct) {
            short8 b8 = ld8(W2b + (((w * 2 + ct) * 8 + kc) * 64 + lane) * 8);
#pragma unroll
            for (int rt = 0; rt < 4; ++rt) acc2[rt][ct] = mfma16(a8[rt], b8, acc2[rt][ct]);
        }
    }
    {
        float b2v[2] = { b2[c0 + l15], b2[c0 + 16 + l15] };
        unsigned short stg[4][2][4];
#pragma unroll
        for (int rt = 0; rt < 4; ++rt)
#pragma unroll
            for (int ct = 0; ct < 2; ++ct)
#pragma unroll
                for (int r = 0; r < 4; ++r)
                    stg[rt][ct][r] = f2bf(fmaxf(acc2[rt][ct][r] + b2v[ct], 0.f));
        __syncthreads();
#pragma unroll
        for (int rt = 0; rt < 4; ++rt)
#pragma unroll
            for (int ct = 0; ct < 2; ++ct)
#pragma unroll
                for (int r = 0; r < 4; ++r)
                    hb[(rt * 16 + q * 4 + r) * HS + c0 + ct * 16 + l15] = stg[rt][ct][r];
    }
    __syncthreads();
    // ---- init: hb @ Winit^T + binit -> h0g/h1g (torch view interleave) ----
    fvec4 a3[4][4];
#pragma unroll
    for (int rt = 0; rt < 4; ++rt)
#pragma unroll
        for (int ct = 0; ct < 4; ++ct) a3[rt][ct] = fz;
#pragma unroll 1
    for (int kc = 0; kc < 8; ++kc) {
        const int k0 = kc * 32 + q * 8;
        short8 a8[4];
#pragma unroll
        for (int rt = 0; rt < 4; ++rt) a8[rt] = ld8(hb + (rt * 16 + l15) * HS + k0);
#pragma unroll
        for (int ct = 0; ct < 4; ++ct) {
            short8 b8 = ld8(Winitb + (((w * 4 + ct) * 8 + kc) * 64 + lane) * 8);
#pragma unroll
            for (int rt = 0; rt < 4; ++rt) a3[rt][ct] = mfma16(a8[rt], b8, a3[rt][ct]);
        }
    }
    const int c0i = w * 64;
#pragma unroll
    for (int ct = 0; ct < 4; ++ct) {
        const int j = c0i + ct * 16 + l15;
        const float bz = binit[j];
        const int half = j >> 8, cc = j & 255;
#pragma unroll
        for (int rt = 0; rt < 4; ++rt)
#pragma unroll
            for (int r = 0; r < 4; ++r) {
                const int i = rows0 + rt * 16 + q * 4 + r;
                const unsigned short v = f2bf(a3[rt][ct][r] + bz);
                if (i < 16384) h0g[(2 * i + half) * 256 + cc] = v;
                else           h1g[(2 * (i - 16384) + half) * 256 + cc] = v;
            }
    }
}

// ---------------- fused 10-step rollout (v13, best measured) ----------------
// 512 blocks x 1024 threads (16 waves, 4 waves/SIMD); wave = 64 rows x 16
// cols; 64 AGPR acc + 64 arch; double-buffered h0/h1 (3 barriers/step).
// Step layout: [phase A: w<4 logits(t-1)+softmax->avs  ||  all: cell0-hh]
//              bar; action-GEMM + cell0 epilogue -> h0n; bar;
//              cell1 (ih+hh) + epilogue -> h1n; bar. Final logits post-loop.
__global__ __launch_bounds__(1024, 4) void k_roll(
    const unsigned short* __restrict__ h0g, const unsigned short* __restrict__ h1g,
    const unsigned short* __restrict__ Wih0b, const unsigned short* __restrict__ Whh0b,
    const unsigned short* __restrict__ Wih1b, const unsigned short* __restrict__ Whh1b,
    const unsigned short* __restrict__ Wab,
    const float* __restrict__ bih0, const float* __restrict__ bhh0,
    const float* __restrict__ bih1, const float* __restrict__ bhh1,
    const float* __restrict__ ba, float* __restrict__ out)
{
    __shared__ unsigned short h0sb[2][64 * HS];
    __shared__ unsigned short h1sb[2][64 * HS];
    __shared__ unsigned short avs[64 * 8];
    __shared__ float ldsb[2048];    // [cell0: br,bz,bi,bh][cell1: same] x 256
    const int tid = threadIdx.x, lane = tid & 63, w = tid >> 6;   // w: 0..15
    const int l15 = lane & 15, q = lane >> 4;
    const int rows0 = blockIdx.x * 64;
    const int c = w * 16 + l15;          // this wave's column for epilogues
    const fvec4 fz = {0.f, 0.f, 0.f, 0.f};
    const short8 z8 = {0,0,0,0,0,0,0,0};

    // ---- h state global -> LDS buffer 0; biases -> LDS ----
    for (int it = tid; it < 64 * 32; it += 1024) {
        const int row = it >> 5, g = (it & 31) * 8;
        *reinterpret_cast<short8*>(&h0sb[0][row * HS + g]) = ld8(h0g + (rows0 + row) * 256 + g);
        *reinterpret_cast<short8*>(&h1sb[0][row * HS + g]) = ld8(h1g + (rows0 + row) * 256 + g);
    }
    if (tid < 256) {
        const int j = tid;
        ldsb[j]       = bih0[j] + bhh0[j];
        ldsb[256 + j] = bih0[256 + j] + bhh0[256 + j];
        ldsb[512 + j] = bih0[512 + j];
        ldsb[768 + j] = bhh0[512 + j];
    } else if (tid < 512) {
        const int j = tid - 256;
        ldsb[1024 + j] = bih1[j] + bhh1[j];
        ldsb[1280 + j] = bih1[256 + j] + bhh1[256 + j];
        ldsb[1536 + j] = bih1[512 + j];
        ldsb[1792 + j] = bhh1[512 + j];
    }
    const float bav = ba[l15 & 7];
    __syncthreads();

    for (int t = 0; t < 10; ++t) {
        const int cur = t & 1, nxt = cur ^ 1;
        const unsigned short* h0c = h0sb[cur];
        unsigned short*       h0n = h0sb[nxt];
        const unsigned short* h1c = h1sb[cur];
        unsigned short*       h1n = h1sb[nxt];
        // ===== phase A: w<4 compute logits(t-1)+softmax->avs from h1c =======
        if (t > 0 && w < 4) {
            fvec4 f = fz;
#pragma unroll 1
            for (int kc = 0; kc < 8; ++kc) {
                const int k0 = kc * 32 + q * 8;
                short8 a8 = ld8(h1c + (w * 16 + l15) * HS + k0);
                short8 b8 = ld8(Wab + (l15 & 7) * 256 + k0);   // cols 8-15 dup, ignored
                f = mfma16(a8, b8, f);
            }
#pragma unroll
            for (int r = 0; r < 4; ++r) {
                float s = f[r] + bav;
                float m = s;
                m = fmaxf(m, __shfl_xor(m, 1, 64));
                m = fmaxf(m, __shfl_xor(m, 2, 64));
                m = fmaxf(m, __shfl_xor(m, 4, 64));
                float e = __expf(s - m);
                float se = e;
                se += __shfl_xor(se, 1, 64);
                se += __shfl_xor(se, 2, 64);
                se += __shfl_xor(se, 4, 64);
                if (l15 < 8) {
                    const int lrow = w * 16 + q * 4 + r;
                    out[(rows0 + lrow) * 80 + (t - 1) * 8 + l15] = s;
                    avs[lrow * 8 + l15] = f2bf(e * __builtin_amdgcn_rcpf(se));
                }
            }
        }
        // ===== all waves: cell0 acc init + hh sweep (h0c x Whh0) ============
        fvec4 aR[4], aZ[4], aNi[4], aNh[4];
        {
            const float vr = ldsb[c],       vz = ldsb[256 + c];
            const float vi = ldsb[512 + c], vh = ldsb[768 + c];
#pragma unroll
            for (int rt = 0; rt < 4; ++rt) {
                aR[rt]  = splat4(vr);
                aZ[rt]  = splat4(vz);
                aNi[rt] = splat4(vi);
                aNh[rt] = splat4(vh);
            }
        }
#pragma unroll 2
        for (int kc = 0; kc < 8; ++kc) {
            const int k0 = kc * 32 + q * 8;
            const unsigned short* wp =
                Whh0b + (((w * 8 + kc) * 64 + lane) * 8);
            const short8 wr = ld8(wp);
            const short8 wz = ld8(wp + 65536);
            const short8 wn = ld8(wp + 131072);
#pragma unroll
            for (int rt = 0; rt < 4; ++rt) {
                const short8 ah = ld8(h0c + (rt * 16 + l15) * HS + k0);
                aR[rt]  = mfma16(ah, wr, aR[rt]);
                aZ[rt]  = mfma16(ah, wz, aZ[rt]);
                aNh[rt] = mfma16(ah, wn, aNh[rt]);
            }
        }
        __syncthreads();   // avs visible (and phase-A h1c reads done)
        // ===== action GEMM (reads avs) + cell0 epilogue -> h0n ==============
        if (t > 0) {
            const unsigned short* wp = Wih0b + c * 8;
            const short8 wr = ld8(wp);
            const short8 wz = ld8(wp + 2048);
            const short8 wn = ld8(wp + 4096);
#pragma unroll
            for (int rt = 0; rt < 4; ++rt) {
                short8 v = ld8(avs + (rt * 16 + l15) * 8);
                const short8 av = (q == 0) ? v : z8;
                aR[rt]  = mfma16(av, wr, aR[rt]);
                aZ[rt]  = mfma16(av, wz, aZ[rt]);
                aNi[rt] = mfma16(av, wn, aNi[rt]);
            }
        }
#pragma unroll
        for (int rt = 0; rt < 4; ++rt)
#pragma unroll
            for (int r = 0; r < 4; ++r) {
                const int row = rt * 16 + q * 4 + r;
                const float hold = bf2f(h0c[row * HS + c]);
                const float rr = sigm(aR[rt][r]);
                const float zz = sigm(aZ[rt][r]);
                const float nn = tanh_f(aNi[rt][r] + rr * aNh[rt][r]);
                h0n[row * HS + c] = f2bf((1.f - zz) * nn + zz * hold);
            }
        __syncthreads();   // h0n visible
        // ===== GRU cell 1: read h0n/h1c, write h1n (own 16 cols) ============
        {
            fvec4 bR[4], bZ[4], bNi[4], bNh[4];
            {
                const float vr = ldsb[1024 + c], vz = ldsb[1280 + c];
                const float vi = ldsb[1536 + c], vh = ldsb[1792 + c];
#pragma unroll
                for (int rt = 0; rt < 4; ++rt) {
                    bR[rt]  = splat4(vr);
                    bZ[rt]  = splat4(vz);
                    bNi[rt] = splat4(vi);
                    bNh[rt] = splat4(vh);
                }
            }
            // ih sweep: h0n x Wih1 -> R, Z, Ni
#pragma unroll 2
            for (int kc = 0; kc < 8; ++kc) {
                const int k0 = kc * 32 + q * 8;
                const unsigned short* wi =
                    Wih1b + (((w * 8 + kc) * 64 + lane) * 8);
                const short8 wir = ld8(wi);
                const short8 wiz = ld8(wi + 65536);
                const short8 win = ld8(wi + 131072);
#pragma unroll
                for (int rt = 0; rt < 4; ++rt) {
                    const short8 ai = ld8(h0n + (rt * 16 + l15) * HS + k0);
                    bR[rt]  = mfma16(ai, wir, bR[rt]);
                    bZ[rt]  = mfma16(ai, wiz, bZ[rt]);
                    bNi[rt] = mfma16(ai, win, bNi[rt]);
                }
            }
            // hh sweep: h1c x Whh1 -> R, Z, Nh
#pragma unroll 2
            for (int kc = 0; kc < 8; ++kc) {
                const int k0 = kc * 32 + q * 8;
                const unsigned short* wh =
                    Whh1b + (((w * 8 + kc) * 64 + lane) * 8);
                const short8 whr = ld8(wh);
                const short8 whz = ld8(wh + 65536);
                const short8 whn = ld8(wh + 131072);
#pragma unroll
                for (int rt = 0; rt < 4; ++rt) {
                    const short8 ah = ld8(h1c + (rt * 16 + l15) * HS + k0);
                    bR[rt]  = mfma16(ah, whr, bR[rt]);
                    bZ[rt]  = mfma16(ah, whz, bZ[rt]);
                    bNh[rt] = mfma16(ah, whn, bNh[rt]);
                }
            }
            // epilogue: write new h1 (own 16 cols) into the other buffer
#pragma unroll
            for (int rt = 0; rt < 4; ++rt)
#pragma unroll
                for (int r = 0; r < 4; ++r) {
                    const int row = rt * 16 + q * 4 + r;
                    const float hold = bf2f(h1c[row * HS + c]);
                    const float rr = sigm(bR[rt][r]);
                    const float zz = sigm(bZ[rt][r]);
                    const float nn = tanh_f(bNi[rt][r] + rr * bNh[rt][r]);
                    h1n[row * HS + c] = f2bf((1.f - zz) * nn + zz * hold);
                }
        }
        __syncthreads();   // h1n visible (next phase A / next step reads it)
    }
    // ===== final logits (t=9) from h1 after step 9 (= h1sb[0]) ==============
    if (w < 4) {
        const unsigned short* h1f = h1sb[0];
        fvec4 f = fz;
#pragma unroll 1
        for (int kc = 0; kc < 8; ++kc) {
            const int k0 = kc * 32 + q * 8;
            short8 a8 = ld8(h1f + (w * 16 + l15) * HS + k0);
            short8 b8 = ld8(Wab + (l15 & 7) * 256 + k0);
            f = mfma16(a8, b8, f);
        }
#pragma unroll
        for (int r = 0; r < 4; ++r) {
            if (l15 < 8) {
                const int lrow = w * 16 + q * 4 + r;
                out[(rows0 + lrow) * 80 + 72 + l15] = f[r] + bav;
            }
        }
    }
}

// ---------------- host side -----------------------------------------------
extern "C" void kernel_launch(void* const* d_in, const int* in_sizes, int n_in,
                              void* d_out, int out_size, void* d_ws, size_t ws_size,
                              hipStream_t stream)
{
    const float* ini   = (const float*)d_in[0];
    const float* fin   = (const float*)d_in[1];
    /* d_in[2] = horizon (always 10) */
    const float* W1    = (const float*)d_in[3];
    const float* b1    = (const float*)d_in[4];
    const float* lng   = (const float*)d_in[5];
    const float* lnb   = (const float*)d_in[6];
    const float* W2    = (const float*)d_in[7];
    const float* b2    = (const float*)d_in[8];
    const float* Wih0  = (const float*)d_in[9];
    const float* Whh0  = (const float*)d_in[10];
    const float* bih0  = (const float*)d_in[11];
    const float* bhh0  = (const float*)d_in[12];
    const float* Wih1  = (const float*)d_in[13];
    const float* Whh1  = (const float*)d_in[14];
    const float* bih1  = (const float*)d_in[15];
    const float* bhh1  = (const float*)d_in[16];
    const float* Wa    = (const float*)d_in[17];
    const float* ba    = (const float*)d_in[18];
    const float* Winit = (const float*)d_in[19];
    const float* binit = (const float*)d_in[20];
    float* out = (float*)d_out;

    char* ws = (char*)d_ws;
    unsigned short* wb     = (unsigned short*)ws;
    unsigned short* W1b    = wb;
    unsigned short* W2b    = wb + 262144;
    unsigned short* Winitb = wb + 327680;
    unsigned short* Wih0b  = wb + 458752;
    unsigned short* Whh0b  = wb + 464896;
    unsigned short* Wih1b  = wb + 661504;
    unsigned short* Whh1b  = wb + 858112;
    unsigned short* Wab    = wb + 1054720;
    unsigned short* h0g = (unsigned short*)(ws + 2113536);
    unsigned short* h1g = (unsigned short*)(ws + 18890752);

    k_prep<<<dim3(4128), dim3(256), 0, stream>>>(W1, W2, Winit, Wih0, Whh0, Wih1, Whh1, Wa, wb);
    k_encode<<<dim3(512), dim3(512), 0, stream>>>(ini, fin, W1b, b1, lng, lnb, W2b, b2,
                                                  Winitb, binit, h0g, h1g);
    k_roll<<<dim3(512), dim3(1024), 0, stream>>>(h0g, h1g, Wih0b, Whh0b, Wih1b, Whh1b, Wab,
                                                 bih0, bhh0, bih1, bhh1, ba, out);
}